// Round 8
// baseline (122.819 us; speedup 1.0000x reference)
//
#include <hip/hip_runtime.h>
#include <math.h>

// DiffKS: time-varying 7-tap sparse IIR.
//   y[n] = x[n] + sum_{i=0..6} block_i[n] * y[n - zc[n] - i],  zc in [37,97].
// Max lag 103 -> 103-sample state. Linear => segmented superposition:
//   phase1 : per (batch,segment) run 103 unit-state + 1 particular IIRs.
//            wave = sample, lanes = runs -> conflict-free LDS rows.
//   phase23: FUSED per batch (16 blocks x 1024): split-K state composition
//            with states kept in LDS, then 16 waves scan one segment each
//            (private LDS ring, depth-2 raw-input prefetch, VALU coeff
//            recompute). Kills a launch gap + the states HBM round-trip +
//            phase3's 256-block coeff staging.

#define B_    16
#define N_    16384
#define S_    16
#define NSEG  1024
#define NITER 28      // ceil(1024/37)
#define RUNS  104     // 103 unit columns + 1 particular
#define CHUNK 37      // min dependency distance (zc >= 37)

#define TG_FLOATS (B_ * S_ * RUNS * RUNS)
#define ST_FLOATS (B_ * S_ * RUNS)

// ---- shared coeff math (proven round-2..7 formulas) ----
__device__ __forceinline__ void diffks_coeffs(float f0v, float lbg, float lbp,
                                              int n, float4& lo, float4& hi) {
  float g  = 0.99f * lbg;
  float p  = lbp;
  float b0 = g * (1.0f - p);
  float a1 = g * p;
  float f0c = f0v - a1 / (b0 + a1 + 1e-7f);
  int   zc  = (int)floorf(f0c) - 2;
  float alpha = f0c - (float)zc;
  float u0 = alpha;
  float u1 = alpha - 1.0f;
  float u2 = alpha - 2.0f;
  float u3 = alpha - 3.0f;
  float u4 = alpha - 4.0f;
  float u5 = alpha - 5.0f;
  float w0 = u1 * u2 * u3 * u4 * u5 * (-1.0f / 120.0f);
  float w1 = u0 * u2 * u3 * u4 * u5 * ( 1.0f /  24.0f);
  float w2 = u0 * u1 * u3 * u4 * u5 * (-1.0f /  12.0f);
  float w3 = u0 * u1 * u2 * u4 * u5 * ( 1.0f /  12.0f);
  float w4 = u0 * u1 * u2 * u3 * u5 * (-1.0f /  24.0f);
  float w5 = u0 * u1 * u2 * u3 * u4 * ( 1.0f / 120.0f);
  lo.x = b0 * w0;                   // block0
  lo.y = fmaf(b0, w1, a1 * w0);     // block1
  lo.z = fmaf(b0, w2, a1 * w1);     // block2
  lo.w = fmaf(b0, w3, a1 * w2);     // block3
  hi.x = fmaf(b0, w4, a1 * w3);     // block4
  hi.y = fmaf(b0, w5, a1 * w4);     // block5
  hi.z = a1 * w5;                   // block6
  hi.w = __int_as_float((n - 6 - zc) & 255);   // ring base row (pos mod 256)
}

// =================== Phase 1: T matrices (runs-major) ===================
// grid 256 (= b*16+s), block 1024 = 16 waves. Wave w processes samples
// 32t+2w, 32t+2w+1 in round t; lanes 0..51 each own runs 2l, 2l+1 (float2).
// hist[row][run]: position q at row q&255, 104 floats contiguous -> every
// tap read is one contiguous row stripe, conflict-free. Coeffs broadcast.
__global__ __launch_bounds__(1024) void diffks_phase1(
    const float* __restrict__ f0, const float* __restrict__ lb,
    const float* __restrict__ x, float* __restrict__ Tg) {
  const int bs = blockIdx.x;
  const int b  = bs >> 4, s = bs & 15;
  const int n0 = s << 10;
  const int tid = threadIdx.x;

  __shared__ __align__(16) float hist[256 * RUNS];   // 104 KB
  __shared__ float4 sLo[NSEG], sHi[NSEG];            // 32 KB
  __shared__ float  sX[NSEG];                        // 4 KB

  {
    const size_t gi = (size_t)b * N_ + n0 + tid;
    float4 lo, hi;
    diffks_coeffs(f0[gi], lb[2 * gi], lb[2 * gi + 1], tid, lo, hi);
    sLo[tid] = lo; sHi[tid] = hi; sX[tid] = x[gi];
  }
  for (int i = tid; i < 64 * RUNS; i += 1024)
    ((float4*)hist)[i] = float4{0.0f, 0.0f, 0.0f, 0.0f};
  __syncthreads();
  if (tid < 103) hist[(255 - tid) * RUNS + tid] = 1.0f;  // e_r at pos -1-r
  __syncthreads();

  const int w    = tid >> 6;      // wave 0..15
  const int lane = tid & 63;
  const int cl   = 2 * lane;      // run columns cl, cl+1
  const bool act = (lane < 52);
  const bool px  = (lane == 51);  // .y of lane 51 is run 103 (particular)

  for (int t = 0; t < 32; ++t) {
#pragma unroll
    for (int u = 0; u < 2; ++u) {
      const int p = 32 * t + 2 * w + u;       // 32 consecutive samples/round
      const float4 lo = sLo[p];               // wave-uniform -> broadcast
      const float4 hi = sHi[p];
      const float  xv = sX[p];
      if (act) {
        const int base = __float_as_int(hi.w);   // row of oldest tap
        float2 acc;
        acc.x = 0.0f;
        acc.y = px ? xv : 0.0f;
        const float c[7] = {hi.z, hi.y, hi.x, lo.w, lo.z, lo.y, lo.x};
#pragma unroll
        for (int m = 0; m < 7; ++m) {
          const int row = (base + m) & 255;
          const float2 v = *(const float2*)&hist[row * RUNS + cl];
          acc.x = fmaf(c[m], v.x, acc.x);
          acc.y = fmaf(c[m], v.y, acc.y);
        }
        *(float2*)&hist[(p & 255) * RUNS + cl] = acc;
      }
    }
    __syncthreads();   // publish this round's 32 samples to all waves
  }

  // emit RUNS-MAJOR: T[r][j] = run r at position 1023-j (row (255-j)&255)
  float* __restrict__ T = Tg + (size_t)bs * RUNS * RUNS;
  for (int idx = tid; idx < RUNS * RUNS; idx += 1024) {
    const int r = idx / RUNS;
    const int j = idx - r * RUNS;
    T[idx] = (j < 103) ? hist[((255 - j) & 255) * RUNS + r] : 0.0f;
  }
}

// =================== Phase 2+3 fused: compose states, then scan ===================
// grid 16 (batch), block 1024 = 16 waves.
// Part A (threads with q<8, i.e. 832): state_{s+1}[j] = sum_r T[r][j]*cur[r]
//   (cur[103]==1 selects the particular tail); states stay in LDS.
// Part B: wave w scans segment w with a private 512-float mirrored ring;
//   raw inputs prefetched depth-2, coeffs recomputed in VALU. 16 waves/CU
//   hide each other's latency (round-2's 1-wave/CU drain doesn't recur).
__global__ __launch_bounds__(1024) void diffks_phase23(
    const float* __restrict__ Tg, const float* __restrict__ f0,
    const float* __restrict__ lb, const float* __restrict__ x,
    float* __restrict__ y) {
  const int b   = blockIdx.x;
  const int tid = threadIdx.x;
  const int j   = tid % RUNS;      // 0..103
  const int q   = tid / RUNS;      // 0..9
  const bool a2 = (q < 8);
  const int r0  = 13 * q;

  __shared__ float stAll[S_ * RUNS];          // 6.7 KB: incoming state per seg
  __shared__ float cur[RUNS];
  __shared__ float part[8][105];              // stride 105: conflict-free
  __shared__ __align__(16) float ring[16 * 512];  // 32 KB: per-wave rings

  if (tid < 103) cur[tid] = 0.0f;
  if (tid == 103) cur[103] = 1.0f;            // particular weight
  __syncthreads();

  const float* __restrict__ Tb = Tg + (size_t)b * S_ * RUNS * RUNS;
  float tvA[13], tvB[13];
#pragma unroll
  for (int k = 0; k < 13; ++k) {
    tvA[k] = a2 ? Tb[(size_t)(r0 + k) * RUNS + j] : 0.0f;
    tvB[k] = a2 ? Tb[(size_t)RUNS * RUNS + (size_t)(r0 + k) * RUNS + j] : 0.0f;
  }

#pragma unroll
  for (int s = 0; s < S_; ++s) {
    float* tv = (s & 1) ? tvB : tvA;
    if (q == 0) stAll[s * RUNS + j] = cur[j];   // state entering segment s
    float acc = 0.0f;
#pragma unroll
    for (int k = 0; k < 13; ++k) acc = fmaf(tv[k], cur[r0 + k], acc);
    if (s + 2 < S_) {                            // prefetch segment s+2
      const float* __restrict__ Tn = Tb + (size_t)(s + 2) * RUNS * RUNS;
#pragma unroll
      for (int k = 0; k < 13; ++k)
        tv[k] = a2 ? Tn[(size_t)(r0 + k) * RUNS + j] : 0.0f;
    }
    if (a2) part[q][j] = acc;
    __syncthreads();
    if (q == 0) {
      float v = 0.0f;
#pragma unroll
      for (int qq = 0; qq < 8; ++qq) v += part[qq][j];
      cur[j] = (j < 103) ? v : 1.0f;
    }
    __syncthreads();   // also publishes stAll[s] before Part B
  }

  // ---- Part B: wave w scans segment w ----
  const int w    = tid >> 6;
  const int lane = tid & 63;
  float* __restrict__ R = ring + (w << 9);    // private 512-float ring

#pragma unroll
  for (int i = 0; i < 8; ++i) R[lane + 64 * i] = 0.0f;
  __builtin_amdgcn_wave_barrier();
  asm volatile("" ::: "memory");
  // incoming state k at segment-local pos -1-k -> row 255-k (+ mirror 256)
  {
    if (lane < 103) {
      const float v = stAll[w * RUNS + lane];
      R[255 - lane] = v; R[511 - lane] = v;
    }
    if (lane < 39) {
      const float v = stAll[w * RUNS + lane + 64];
      R[191 - lane] = v; R[447 - lane] = v;
    }
  }
  __builtin_amdgcn_wave_barrier();
  asm volatile("" ::: "memory");

  const int n0 = w << 10;                     // segment base (mod 256 == 0)
  const size_t gb = (size_t)b * N_ + n0;
  const float*  __restrict__ f0b = f0 + gb;
  const float2* __restrict__ lbb = (const float2*)(lb + 2 * gb);
  const float*  __restrict__ xb  = x + gb;
  float*        __restrict__ yb  = y + gb;
  const bool al = (lane < CHUNK);

  // depth-2 raw-input prefetch
  float  rf[2]; float2 rl[2]; float rx[2];
  if (al) {
    rf[0] = f0b[lane];          rl[0] = lbb[lane];          rx[0] = xb[lane];
    rf[1] = f0b[lane + CHUNK];  rl[1] = lbb[lane + CHUNK];  rx[1] = xb[lane + CHUNK];
  }

  for (int t = 0; t < NITER; ++t) {
    const int p = t * CHUNK + lane;
    const int st = t & 1;
    const float  cf = rf[st];
    const float2 cl2 = rl[st];
    const float  cx = rx[st];
    {
      const int p2 = p + 2 * CHUNK;
      if (al && p2 < NSEG) {
        rf[st] = f0b[p2]; rl[st] = lbb[p2]; rx[st] = xb[p2];
      }
    }
    if (al && p < NSEG) {
      float4 lo, hi;
      diffks_coeffs(cf, cl2.x, cl2.y, p, lo, hi);
      const int base = __float_as_int(hi.w);   // (p-6-zc)&255
      const float t0 = R[base + 0];
      const float t1 = R[base + 1];
      const float t2 = R[base + 2];
      const float t3 = R[base + 3];
      const float t4 = R[base + 4];
      const float t5 = R[base + 5];
      const float t6 = R[base + 6];
      const float s0 = fmaf(lo.x, t6, cx);
      const float s1 = fmaf(lo.y, t5, lo.z * t4);
      const float s2 = fmaf(lo.w, t3, hi.x * t2);
      const float s3 = fmaf(hi.y, t1, hi.z * t0);
      const float yv = (s0 + s1) + (s2 + s3);
      const int wsl = p & 255;
      R[wsl]       = yv;
      R[wsl + 256] = yv;
      yb[p] = yv;
    }
    __builtin_amdgcn_wave_barrier();
    asm volatile("" ::: "memory");
  }
}

// =================== Fallback (proven round-2 path) ===================
__global__ __launch_bounds__(256) void diffks_coeff_fb(
    const float* __restrict__ f0, const float* __restrict__ lb,
    float* __restrict__ cw, int total, int Nmask) {
  int idx = blockIdx.x * blockDim.x + threadIdx.x;
  if (idx >= total) return;
  float4 lo, hi;
  diffks_coeffs(f0[idx], lb[2 * idx], lb[2 * idx + 1], idx & Nmask, lo, hi);
  float4* out4 = (float4*)cw;
  out4[2 * idx]     = lo;
  out4[2 * idx + 1] = hi;
}

__global__ __launch_bounds__(64) void diffks_scan_fb(
    const float* __restrict__ x, const float* __restrict__ cw,
    float* __restrict__ y, int N) {
  const int b    = blockIdx.x;
  const int lane = threadIdx.x;
  __shared__ float ring[512];
#pragma unroll
  for (int i = 0; i < 8; ++i) ring[lane + 64 * i] = 0.0f;
  __builtin_amdgcn_wave_barrier();
  asm volatile("" ::: "memory");
  const float4* __restrict__ c4 = (const float4*)(cw + (size_t)b * N * 8);
  const float*  __restrict__ xb = x + (size_t)b * N;
  float*        __restrict__ yb = y + (size_t)b * N;
  const bool act = (lane < CHUNK);
  const int nIter = (N + CHUNK - 1) / CHUNK;
  for (int t = 0; t < nIter; ++t) {
    const int n = t * CHUNK + lane;
    if (act && n < N) {
      const float4 lo = c4[2 * n];
      const float4 hi = c4[2 * n + 1];
      const float  xv = xb[n];
      const int base = __float_as_int(hi.w);
      const float r0 = ring[base + 0];
      const float r1 = ring[base + 1];
      const float r2 = ring[base + 2];
      const float r3 = ring[base + 3];
      const float r4 = ring[base + 4];
      const float r5 = ring[base + 5];
      const float r6 = ring[base + 6];
      const float s0 = fmaf(lo.x, r6, xv);
      const float s1 = fmaf(lo.y, r5, lo.z * r4);
      const float s2 = fmaf(lo.w, r3, hi.x * r2);
      const float s3 = fmaf(hi.y, r1, hi.z * r0);
      const float yv = (s0 + s1) + (s2 + s3);
      ring[n & 255]         = yv;
      ring[(n & 255) + 256] = yv;
      yb[n] = yv;
    }
    __builtin_amdgcn_wave_barrier();
    asm volatile("" ::: "memory");
  }
}

extern "C" void kernel_launch(void* const* d_in, const int* in_sizes, int n_in,
                              void* d_out, int out_size, void* d_ws, size_t ws_size,
                              hipStream_t stream) {
  const float* f0 = (const float*)d_in[0];
  const float* x  = (const float*)d_in[1];
  const float* lb = (const float*)d_in[2];
  float* out = (float*)d_out;

  const int total = in_sizes[0];
  const size_t need = (size_t)(TG_FLOATS + ST_FLOATS) * 4;

  if (total == B_ * N_ && ws_size >= need) {
    float* Tg = (float*)d_ws;
    diffks_phase1<<<B_ * S_, 1024, 0, stream>>>(f0, lb, x, Tg);
    diffks_phase23<<<B_, 1024, 0, stream>>>(Tg, f0, lb, x, out);
  } else {
    const int N = total / B_;
    float* cw = (float*)d_ws;
    diffks_coeff_fb<<<(total + 255) / 256, 256, 0, stream>>>(f0, lb, cw, total, N - 1);
    diffks_scan_fb<<<B_, 64, 0, stream>>>(x, cw, out, N);
  }
}

// Round 9
// 105.209 us; speedup vs baseline: 1.1674x; 1.1674x over previous
//
#include <hip/hip_runtime.h>
#include <math.h>

// DiffKS: time-varying 7-tap sparse IIR.
//   y[n] = x[n] + sum_{i=0..6} block_i[n] * y[n - zc[n] - i],  zc in [37,97].
// Max lag 103 -> 103-sample state. Linear => segmented superposition:
//   phase1: per (batch,segment) run 103 unit-state + 1 particular IIRs.
//           wave = sample, lanes = runs -> conflict-free LDS row reads.
//   phase2: serial state composition, coalesced split-K. SPILL-PROOF: the
//           16 steps are expanded via unrolled macro so tvA/tvB are always
//           statically indexed (round-8's pointer-select demoted the
//           register arrays to scratch -> VGPR_Count=32 + 53us kernel).
//   phase3: exact per-segment re-run with known incoming state (256 blocks).

#define B_    16
#define N_    16384
#define S_    16
#define NSEG  1024
#define NITER 28      // ceil(1024/37) for phase3
#define RUNS  104     // 103 unit columns + 1 particular
#define CHUNK 37      // min dependency distance (zc >= 37)

#define TG_FLOATS (B_ * S_ * RUNS * RUNS)
#define ST_FLOATS (B_ * S_ * RUNS)

// ---- shared coeff math (proven round-2..8 formulas) ----
__device__ __forceinline__ void diffks_coeffs(float f0v, float lbg, float lbp,
                                              int n, float4& lo, float4& hi) {
  float g  = 0.99f * lbg;
  float p  = lbp;
  float b0 = g * (1.0f - p);
  float a1 = g * p;
  float f0c = f0v - a1 / (b0 + a1 + 1e-7f);
  int   zc  = (int)floorf(f0c) - 2;
  float alpha = f0c - (float)zc;
  float u0 = alpha;
  float u1 = alpha - 1.0f;
  float u2 = alpha - 2.0f;
  float u3 = alpha - 3.0f;
  float u4 = alpha - 4.0f;
  float u5 = alpha - 5.0f;
  float w0 = u1 * u2 * u3 * u4 * u5 * (-1.0f / 120.0f);
  float w1 = u0 * u2 * u3 * u4 * u5 * ( 1.0f /  24.0f);
  float w2 = u0 * u1 * u3 * u4 * u5 * (-1.0f /  12.0f);
  float w3 = u0 * u1 * u2 * u4 * u5 * ( 1.0f /  12.0f);
  float w4 = u0 * u1 * u2 * u3 * u5 * (-1.0f /  24.0f);
  float w5 = u0 * u1 * u2 * u3 * u4 * ( 1.0f / 120.0f);
  lo.x = b0 * w0;                   // block0
  lo.y = fmaf(b0, w1, a1 * w0);     // block1
  lo.z = fmaf(b0, w2, a1 * w1);     // block2
  lo.w = fmaf(b0, w3, a1 * w2);     // block3
  hi.x = fmaf(b0, w4, a1 * w3);     // block4
  hi.y = fmaf(b0, w5, a1 * w4);     // block5
  hi.z = a1 * w5;                   // block6
  hi.w = __int_as_float((n - 6 - zc) & 255);   // ring base row (pos mod 256)
}

// =================== Phase 1: T matrices (runs-major) ===================
// grid 256 (= b*16+s), block 1024 = 16 waves. Wave w processes samples
// 32t+2w, 32t+2w+1 in round t; lanes 0..51 each own runs 2l, 2l+1 (float2).
// hist[row][run]: position q at row q&255, 104 floats contiguous -> every
// tap read is one contiguous row stripe, conflict-free. Coeffs broadcast.
// (measured ~27us; byte-floor ~13us — unchanged from round 7)
__global__ __launch_bounds__(1024) void diffks_phase1(
    const float* __restrict__ f0, const float* __restrict__ lb,
    const float* __restrict__ x, float* __restrict__ Tg) {
  const int bs = blockIdx.x;
  const int b  = bs >> 4, s = bs & 15;
  const int n0 = s << 10;
  const int tid = threadIdx.x;

  __shared__ __align__(16) float hist[256 * RUNS];   // 104 KB
  __shared__ float4 sLo[NSEG], sHi[NSEG];            // 32 KB
  __shared__ float  sX[NSEG];                        // 4 KB

  {
    const size_t gi = (size_t)b * N_ + n0 + tid;
    float4 lo, hi;
    diffks_coeffs(f0[gi], lb[2 * gi], lb[2 * gi + 1], tid, lo, hi);
    sLo[tid] = lo; sHi[tid] = hi; sX[tid] = x[gi];
  }
  for (int i = tid; i < 64 * RUNS; i += 1024)
    ((float4*)hist)[i] = float4{0.0f, 0.0f, 0.0f, 0.0f};
  __syncthreads();
  if (tid < 103) hist[(255 - tid) * RUNS + tid] = 1.0f;  // e_r at pos -1-r
  __syncthreads();

  const int w    = tid >> 6;      // wave 0..15
  const int lane = tid & 63;
  const int cl   = 2 * lane;      // run columns cl, cl+1
  const bool act = (lane < 52);
  const bool px  = (lane == 51);  // .y of lane 51 is run 103 (particular)

  for (int t = 0; t < 32; ++t) {
#pragma unroll
    for (int u = 0; u < 2; ++u) {
      const int p = 32 * t + 2 * w + u;       // 32 consecutive samples/round
      const float4 lo = sLo[p];               // wave-uniform -> broadcast
      const float4 hi = sHi[p];
      const float  xv = sX[p];
      if (act) {
        const int base = __float_as_int(hi.w);   // row of oldest tap
        float2 acc;
        acc.x = 0.0f;
        acc.y = px ? xv : 0.0f;
        const float c[7] = {hi.z, hi.y, hi.x, lo.w, lo.z, lo.y, lo.x};
#pragma unroll
        for (int m = 0; m < 7; ++m) {
          const int row = (base + m) & 255;
          const float2 v = *(const float2*)&hist[row * RUNS + cl];
          acc.x = fmaf(c[m], v.x, acc.x);
          acc.y = fmaf(c[m], v.y, acc.y);
        }
        *(float2*)&hist[(p & 255) * RUNS + cl] = acc;
      }
    }
    __syncthreads();   // publish this round's 32 samples to all waves
  }

  // emit RUNS-MAJOR: T[r][j] = run r at position 1023-j (row (255-j)&255)
  float* __restrict__ T = Tg + (size_t)bs * RUNS * RUNS;
  for (int idx = tid; idx < RUNS * RUNS; idx += 1024) {
    const int r = idx / RUNS;
    const int j = idx - r * RUNS;
    T[idx] = (j < 103) ? hist[((255 - j) & 255) * RUNS + r] : 0.0f;
  }
}

// =================== Phase 2: serial state composition ===================
// grid 16 (batch), block 832 = 104 j-threads x 8 k-slices.
// state_{s+1}[j] = sum_{r=0..103} T[r][j] * cur[r], with cur[103] == 1
// (run 103 is the particular tail). Lanes = consecutive j -> coalesced loads.
// Double-buffered prefetch with GUARANTEED static register indexing: the
// step body is a macro naming tvA/tvB directly, expanded by an unrolled
// pair loop. No pointer select anywhere -> no scratch demotion.
#define P2_STEP(s_, tv_)                                                      \
  {                                                                           \
    if (q == 0) states[((size_t)b * S_ + (s_)) * RUNS + j] = cur[j];          \
    float acc = 0.0f;                                                         \
    _Pragma("unroll")                                                         \
    for (int k = 0; k < 13; ++k) acc = fmaf(tv_[k], cur[r0 + k], acc);        \
    if ((s_) + 2 < S_) {                                                      \
      const float* __restrict__ Tn = Tb + (size_t)((s_) + 2) * RUNS * RUNS;   \
      _Pragma("unroll")                                                       \
      for (int k = 0; k < 13; ++k) tv_[k] = Tn[(size_t)(r0 + k) * RUNS + j];  \
    }                                                                         \
    part[q][j] = acc;                                                         \
    __syncthreads();                                                          \
    if (q == 0) {                                                             \
      float v = 0.0f;                                                         \
      _Pragma("unroll")                                                       \
      for (int qq = 0; qq < 8; ++qq) v += part[qq][j];                        \
      cur[j] = (j < 103) ? v : 1.0f;                                          \
    }                                                                         \
    __syncthreads();                                                          \
  }

__global__ __launch_bounds__(832) void diffks_phase2(
    const float* __restrict__ Tg, float* __restrict__ states) {
  const int b   = blockIdx.x;
  const int tid = threadIdx.x;
  const int j   = tid % RUNS;      // 0..103
  const int q   = tid / RUNS;      // 0..7
  const int r0  = 13 * q;
  __shared__ float cur[RUNS];
  __shared__ float part[8][105];   // 105 stride: conflict-free reduce
  if (tid < 103) cur[tid] = 0.0f;
  if (tid == 103) cur[103] = 1.0f; // particular weight, never overwritten
  __syncthreads();

  const float* __restrict__ Tb = Tg + (size_t)b * S_ * RUNS * RUNS;
  float tvA[13], tvB[13];
#pragma unroll
  for (int k = 0; k < 13; ++k)
    tvA[k] = Tb[(size_t)(r0 + k) * RUNS + j];                       // seg 0
#pragma unroll
  for (int k = 0; k < 13; ++k)
    tvB[k] = Tb[(size_t)RUNS * RUNS + (size_t)(r0 + k) * RUNS + j]; // seg 1

#pragma unroll
  for (int sp = 0; sp < 8; ++sp) {
    P2_STEP(2 * sp,     tvA)
    P2_STEP(2 * sp + 1, tvB)
  }
}

// =================== Phase 3: exact per-segment re-run ===================
// grid 256, block 256 (4 waves): all stage coeffs (recomputed), wave 0 runs
// the 28-iter scan, all flush. Staging loop statically unrolled so the 4
// rounds of global loads are batched into one latency window.
__global__ __launch_bounds__(256) void diffks_phase3(
    const float* __restrict__ f0, const float* __restrict__ lb,
    const float* __restrict__ x, const float* __restrict__ states,
    float* __restrict__ y) {
  const int bs = blockIdx.x;
  const int b  = bs >> 4, s = bs & 15;
  const int n0 = s << 10;
  const int tid = threadIdx.x;

  __shared__ __align__(16) float ring[512];   // mirrored mod-256 ring
  __shared__ float4 sC[2 * NSEG];             // interleaved lo/hi
  __shared__ float  sX[NSEG];
  __shared__ float  sY[NSEG];

#pragma unroll
  for (int k = 0; k < 2; ++k) ring[tid + 256 * k] = 0.0f;
  {
    const size_t gb = (size_t)b * N_ + n0;
    const float*  __restrict__ f0b = f0 + gb;
    const float2* __restrict__ lbb = (const float2*)(lb + 2 * gb);
    const float*  __restrict__ xb  = x + gb;
    // batch all 4 rounds of loads, then compute
    float  vf[4]; float2 vl[4]; float vx[4];
#pragma unroll
    for (int k = 0; k < 4; ++k) {
      const int i = tid + 256 * k;
      vf[k] = f0b[i]; vl[k] = lbb[i]; vx[k] = xb[i];
    }
#pragma unroll
    for (int k = 0; k < 4; ++k) {
      const int i = tid + 256 * k;
      float4 lo, hi;
      diffks_coeffs(vf[k], vl[k].x, vl[k].y, n0 + i, lo, hi);
      sC[2 * i] = lo; sC[2 * i + 1] = hi; sX[i] = vx[k];
    }
  }
  __syncthreads();
  // incoming state k at position n0-1-k -> row 255-k (+ mirror). Hot-loop
  // writes only reach row 255-k at p=255-k > 102-k = last read of state k.
  const float* __restrict__ st = states + (size_t)bs * RUNS;
  if (tid < 103) {
    const float v = st[tid];
    ring[255 - tid] = v;
    ring[511 - tid] = v;
  }
  __syncthreads();

  if (tid < 64) {
    const int lane = tid;
    const bool act = (lane < CHUNK);
    for (int t = 0; t < NITER; ++t) {
      const int p = t * CHUNK + lane;
      if (act && p < NSEG) {
        const float4 lo = sC[2 * p];
        const float4 hi = sC[2 * p + 1];
        const float  xv = sX[p];
        const int base = __float_as_int(hi.w);   // (p-6-zc)&255
        const float r0 = ring[base + 0];
        const float r1 = ring[base + 1];
        const float r2 = ring[base + 2];
        const float r3 = ring[base + 3];
        const float r4 = ring[base + 4];
        const float r5 = ring[base + 5];
        const float r6 = ring[base + 6];
        const float s0 = fmaf(lo.x, r6, xv);
        const float s1 = fmaf(lo.y, r5, lo.z * r4);
        const float s2 = fmaf(lo.w, r3, hi.x * r2);
        const float s3 = fmaf(hi.y, r1, hi.z * r0);
        const float yv = (s0 + s1) + (s2 + s3);
        const int wsl = p & 255;
        ring[wsl]       = yv;
        ring[wsl + 256] = yv;
        sY[p] = yv;
      }
      __builtin_amdgcn_wave_barrier();
      asm volatile("" ::: "memory");
    }
  }
  __syncthreads();

  float4* __restrict__ yb = (float4*)(y + (size_t)b * N_ + n0);
  yb[tid] = ((const float4*)sY)[tid];
}

// =================== Fallback (proven round-2 path) ===================
__global__ __launch_bounds__(256) void diffks_coeff_fb(
    const float* __restrict__ f0, const float* __restrict__ lb,
    float* __restrict__ cw, int total, int Nmask) {
  int idx = blockIdx.x * blockDim.x + threadIdx.x;
  if (idx >= total) return;
  float4 lo, hi;
  diffks_coeffs(f0[idx], lb[2 * idx], lb[2 * idx + 1], idx & Nmask, lo, hi);
  float4* out4 = (float4*)cw;
  out4[2 * idx]     = lo;
  out4[2 * idx + 1] = hi;
}

__global__ __launch_bounds__(64) void diffks_scan_fb(
    const float* __restrict__ x, const float* __restrict__ cw,
    float* __restrict__ y, int N) {
  const int b    = blockIdx.x;
  const int lane = threadIdx.x;
  __shared__ float ring[512];
#pragma unroll
  for (int i = 0; i < 8; ++i) ring[lane + 64 * i] = 0.0f;
  __builtin_amdgcn_wave_barrier();
  asm volatile("" ::: "memory");
  const float4* __restrict__ c4 = (const float4*)(cw + (size_t)b * N * 8);
  const float*  __restrict__ xb = x + (size_t)b * N;
  float*        __restrict__ yb = y + (size_t)b * N;
  const bool act = (lane < CHUNK);
  const int nIter = (N + CHUNK - 1) / CHUNK;
  for (int t = 0; t < nIter; ++t) {
    const int n = t * CHUNK + lane;
    if (act && n < N) {
      const float4 lo = c4[2 * n];
      const float4 hi = c4[2 * n + 1];
      const float  xv = xb[n];
      const int base = __float_as_int(hi.w);
      const float r0 = ring[base + 0];
      const float r1 = ring[base + 1];
      const float r2 = ring[base + 2];
      const float r3 = ring[base + 3];
      const float r4 = ring[base + 4];
      const float r5 = ring[base + 5];
      const float r6 = ring[base + 6];
      const float s0 = fmaf(lo.x, r6, xv);
      const float s1 = fmaf(lo.y, r5, lo.z * r4);
      const float s2 = fmaf(lo.w, r3, hi.x * r2);
      const float s3 = fmaf(hi.y, r1, hi.z * r0);
      const float yv = (s0 + s1) + (s2 + s3);
      ring[n & 255]         = yv;
      ring[(n & 255) + 256] = yv;
      yb[n] = yv;
    }
    __builtin_amdgcn_wave_barrier();
    asm volatile("" ::: "memory");
  }
}

extern "C" void kernel_launch(void* const* d_in, const int* in_sizes, int n_in,
                              void* d_out, int out_size, void* d_ws, size_t ws_size,
                              hipStream_t stream) {
  const float* f0 = (const float*)d_in[0];
  const float* x  = (const float*)d_in[1];
  const float* lb = (const float*)d_in[2];
  float* out = (float*)d_out;

  const int total = in_sizes[0];
  const size_t need = (size_t)(TG_FLOATS + ST_FLOATS) * 4;

  if (total == B_ * N_ && ws_size >= need) {
    float* Tg = (float*)d_ws;
    float* st = Tg + TG_FLOATS;
    diffks_phase1<<<B_ * S_, 1024, 0, stream>>>(f0, lb, x, Tg);
    diffks_phase2<<<B_, 832, 0, stream>>>(Tg, st);
    diffks_phase3<<<B_ * S_, 256, 0, stream>>>(f0, lb, x, st, out);
  } else {
    const int N = total / B_;
    float* cw = (float*)d_ws;
    diffks_coeff_fb<<<(total + 255) / 256, 256, 0, stream>>>(f0, lb, cw, total, N - 1);
    diffks_scan_fb<<<B_, 64, 0, stream>>>(x, cw, out, N);
  }
}